// Round 5
// baseline (152.088 us; speedup 1.0000x reference)
//
#include <hip/hip_runtime.h>
#include <hip/hip_fp16.h>

#define TMAX 4096
#define ABLOCKS 512          // hist grid: 2 blocks/CU -> 32 waves/CU
#define ATHREADS 1024
#define PERTHREAD_V4 4       // fast path: 4 x float4 per thread (16 samples)

// reduce decomposition: RB buckets per block (one per lane -> 256B coalesced
// wave reads), RS row-slices per bucket
#define RB 64
#define RS 16
#define RBLOCKS (TMAX / RB)  // 64

// ---------------------------------------------------------------------------
// Kernel A: per-block LDS histogram via native f32 LDS atomics (ds_add_f32,
// 1 bank/lane vs 2 for u64) into TWO sub-histograms (waves 0-7 -> A,
// 8-15 -> B) to halve same-bank contention; u32 count atomic only on event
// lanes (~50% active). Flush: packed u32 (cnt<<16 | f16(sum)) -> 8.4 MB.
// Block 0 zeroes the cross-block `done` counter for kernel B.
// ---------------------------------------------------------------------------
__global__ __launch_bounds__(ATHREADS, 8) void coxph_hist_fixed(
    const float* __restrict__ risk, const int* __restrict__ time_,
    const int* __restrict__ event,
    unsigned* __restrict__ ppack, float* __restrict__ pevr,
    unsigned* __restrict__ done)
{
    __shared__ float    s_sumA[TMAX];
    __shared__ float    s_sumB[TMAX];
    __shared__ unsigned s_cnt[TMAX];
    __shared__ float    s_evr[ATHREADS / 64];

    const int tid = threadIdx.x;
    if (blockIdx.x == 0 && tid == 0) *done = 0u;
    #pragma unroll
    for (int k = 0; k < TMAX / ATHREADS; ++k) {
        const int i = tid + k * ATHREADS;
        s_sumA[i] = 0.f; s_sumB[i] = 0.f; s_cnt[i] = 0u;
    }
    __syncthreads();

    float* __restrict__ s_sum = (tid < 512) ? s_sumA : s_sumB;

    const float4* r4 = (const float4*)risk;
    const int4*   t4 = (const int4*)time_;
    const int4*   e4 = (const int4*)event;

    const int base = blockIdx.x * ATHREADS + tid;     // vec4 index
    const int STRIDE4 = ABLOCKS * ATHREADS;           // vec4 stride

    float4 r[PERTHREAD_V4]; int4 t[PERTHREAD_V4]; int4 e[PERTHREAD_V4];
    #pragma unroll
    for (int k = 0; k < PERTHREAD_V4; ++k) {
        const int i = base + k * STRIDE4;
        r[k] = r4[i]; t[k] = t4[i]; e[k] = e4[i];
    }

    float evr = 0.f;
    #pragma unroll
    for (int k = 0; k < PERTHREAD_V4; ++k) {
        {
            int tb = t[k].x & (TMAX - 1);
            atomicAdd(&s_sum[tb], __expf(r[k].x));
            if (e[k].x) { atomicAdd(&s_cnt[tb], 1u); evr += r[k].x; }
        }
        {
            int tb = t[k].y & (TMAX - 1);
            atomicAdd(&s_sum[tb], __expf(r[k].y));
            if (e[k].y) { atomicAdd(&s_cnt[tb], 1u); evr += r[k].y; }
        }
        {
            int tb = t[k].z & (TMAX - 1);
            atomicAdd(&s_sum[tb], __expf(r[k].z));
            if (e[k].z) { atomicAdd(&s_cnt[tb], 1u); evr += r[k].z; }
        }
        {
            int tb = t[k].w & (TMAX - 1);
            atomicAdd(&s_sum[tb], __expf(r[k].w));
            if (e[k].w) { atomicAdd(&s_cnt[tb], 1u); evr += r[k].w; }
        }
    }

    // wave-level reduce of event-risk sum
    #pragma unroll
    for (int off = 32; off > 0; off >>= 1) evr += __shfl_down(evr, off);
    const int lane = tid & 63, wave = tid >> 6;
    if (lane == 0) s_evr[wave] = evr;
    __syncthreads();

    unsigned* pp = ppack + (size_t)blockIdx.x * TMAX;
    #pragma unroll
    for (int k = 0; k < TMAX / ATHREADS; ++k) {
        const int i = tid + k * ATHREADS;
        float s = s_sumA[i] + s_sumB[i];               // partials ~O(10): f16-safe
        unsigned c = s_cnt[i];                         // <= 16384: fits 16 bits
        unsigned hb = (unsigned)__half_as_ushort(__float2half(s));
        pp[i] = (c << 16) | hb;
    }
    if (tid == 0) {
        float tot = 0.f;
        for (int w = 0; w < ATHREADS / 64; ++w) tot += s_evr[w];
        pevr[blockIdx.x] = tot;
    }
}

// ---------------------------------------------------------------------------
// Kernel A' (generic fallback, any n): grid-stride, same scheme.
// ---------------------------------------------------------------------------
__global__ __launch_bounds__(ATHREADS, 8) void coxph_hist_generic(
    const float* __restrict__ risk, const int* __restrict__ time_,
    const int* __restrict__ event,
    unsigned* __restrict__ ppack, float* __restrict__ pevr,
    unsigned* __restrict__ done, int n)
{
    __shared__ float    s_sumA[TMAX];
    __shared__ float    s_sumB[TMAX];
    __shared__ unsigned s_cnt[TMAX];
    __shared__ float    s_evr[ATHREADS / 64];

    const int tid = threadIdx.x;
    if (blockIdx.x == 0 && tid == 0) *done = 0u;
    #pragma unroll
    for (int k = 0; k < TMAX / ATHREADS; ++k) {
        const int i = tid + k * ATHREADS;
        s_sumA[i] = 0.f; s_sumB[i] = 0.f; s_cnt[i] = 0u;
    }
    __syncthreads();

    float* __restrict__ s_sum = (tid < 512) ? s_sumA : s_sumB;

    float evr = 0.f;
    const int stride = gridDim.x * ATHREADS;
    for (int i = blockIdx.x * ATHREADS + tid; i < n; i += stride) {
        float rv = risk[i];
        int   ev = event[i];
        int   tb = time_[i] & (TMAX - 1);
        atomicAdd(&s_sum[tb], __expf(rv));
        if (ev) { atomicAdd(&s_cnt[tb], 1u); evr += rv; }
    }

    #pragma unroll
    for (int off = 32; off > 0; off >>= 1) evr += __shfl_down(evr, off);
    const int lane = tid & 63, wave = tid >> 6;
    if (lane == 0) s_evr[wave] = evr;
    __syncthreads();

    unsigned* pp = ppack + (size_t)blockIdx.x * TMAX;
    #pragma unroll
    for (int k = 0; k < TMAX / ATHREADS; ++k) {
        const int i = tid + k * ATHREADS;
        float s = s_sumA[i] + s_sumB[i];
        unsigned c = s_cnt[i];
        unsigned hb = (unsigned)__half_as_ushort(__float2half(s));
        pp[i] = (c << 16) | hb;
    }
    if (tid == 0) {
        float tot = 0.f;
        for (int w = 0; w < ATHREADS / 64; ++w) tot += s_evr[w];
        pevr[blockIdx.x] = tot;
    }
}

// ---------------------------------------------------------------------------
// Kernel B: reduce partials -> bucket sums/counts; the LAST block to finish
// (device-scope done counter) then performs the suffix-scan + nll finalize.
// 64 blocks x 1024: block owns 64 buckets (one per lane -> 256B coalesced
// wave reads), thread (s,j) sums a 32-row slice, LDS tree across 16 slices.
// ---------------------------------------------------------------------------
__global__ __launch_bounds__(1024) void coxph_reduce_finalize(
    const unsigned* __restrict__ ppack, const float* __restrict__ pevr,
    float* __restrict__ bsum, unsigned* __restrict__ bcnt,
    unsigned* __restrict__ done, float* __restrict__ out)
{
    __shared__ float    ls[RS * RB];
    __shared__ unsigned lc[RS * RB];
    __shared__ unsigned s_last;

    const int t = threadIdx.x;
    const int j = t & (RB - 1);          // bucket lane 0..63
    const int s = t >> 6;                // slice 0..15
    const int bucket = blockIdx.x * RB + j;

    float sum = 0.f; unsigned cnt = 0u;
    #pragma unroll
    for (int k = 0; k < ABLOCKS / RS; ++k) {   // 32 rows per slice
        const int row = s * (ABLOCKS / RS) + k;
        unsigned p = ppack[(size_t)row * TMAX + bucket];
        sum += __half2float(__ushort_as_half((unsigned short)(p & 0xFFFFu)));
        cnt += p >> 16;
    }
    ls[t] = sum; lc[t] = cnt;
    __syncthreads();

    #pragma unroll
    for (int h = RS / 2; h >= 1; h >>= 1) {
        if (s < h) { ls[t] += ls[t + h * RB]; lc[t] += lc[t + h * RB]; }
        __syncthreads();
    }
    if (s == 0) { bsum[bucket] = ls[j]; bcnt[bucket] = lc[j]; }
    __syncthreads();

    if (t == 0) {
        __threadfence();                  // device-scope release
        unsigned old = atomicAdd(done, 1u);
        s_last = (old == RBLOCKS - 1) ? 1u : 0u;
    }
    __syncthreads();
    if (!s_last) return;
    __threadfence();                      // device-scope acquire

    // ---- finalize: suffix-sum over 4096 buckets + nll, within this block ----
    __shared__ float    s_wsum[16];
    __shared__ double   s_dacc[16];
    __shared__ unsigned s_cacc[16];

    const int lane = t & 63, wave = t >> 6;
    const int j0 = 4 * t;
    float v0 = bsum[TMAX - 1 - j0];
    float v1 = bsum[TMAX - 2 - j0];
    float v2 = bsum[TMAX - 3 - j0];
    float v3 = bsum[TMAX - 4 - j0];
    float p0 = v0, p1 = p0 + v1, p2 = p1 + v2, p3 = p2 + v3;

    float t_incl = p3;
    #pragma unroll
    for (int off = 1; off < 64; off <<= 1) {
        float u = __shfl_up(t_incl, off);
        if (lane >= off) t_incl += u;
    }
    if (lane == 63) s_wsum[wave] = t_incl;
    __syncthreads();
    if (t == 0) {
        float acc = 0.f;
        for (int w = 0; w < 16; ++w) { float x = s_wsum[w]; s_wsum[w] = acc; acc += x; }
    }
    __syncthreads();
    const float excl = (t_incl - p3) + s_wsum[wave];

    double acc = 0.0;
    unsigned ctot = 0u;
    unsigned c0 = bcnt[TMAX - 1 - j0];
    unsigned c1 = bcnt[TMAX - 2 - j0];
    unsigned c2 = bcnt[TMAX - 3 - j0];
    unsigned c3 = bcnt[TMAX - 4 - j0];
    if (c0) { acc += (double)c0 * (double)logf(excl + p0); ctot += c0; }
    if (c1) { acc += (double)c1 * (double)logf(excl + p1); ctot += c1; }
    if (c2) { acc += (double)c2 * (double)logf(excl + p2); ctot += c2; }
    if (c3) { acc += (double)c3 * (double)logf(excl + p3); ctot += c3; }

    if (t < ABLOCKS) acc -= (double)pevr[t];   // ABLOCKS=512 <= 1024 threads

    #pragma unroll
    for (int off = 32; off > 0; off >>= 1) {
        acc  += __shfl_down(acc, off);
        ctot += __shfl_down(ctot, off);
    }
    if (lane == 0) { s_dacc[wave] = acc; s_cacc[wave] = ctot; }
    __syncthreads();
    if (t == 0) {
        double a = 0.0; unsigned c = 0u;
        for (int w = 0; w < 16; ++w) { a += s_dacc[w]; c += s_cacc[w]; }
        out[0] = c ? (float)a : 0.0f;
    }
}

// ---------------------------------------------------------------------------
extern "C" void kernel_launch(void* const* d_in, const int* in_sizes, int n_in,
                              void* d_out, int out_size, void* d_ws, size_t ws_size,
                              hipStream_t stream)
{
    const float* risk  = (const float*)d_in[0];
    const int*   time_ = (const int*)d_in[1];
    const int*   event = (const int*)d_in[2];
    float* out = (float*)d_out;
    const int n = in_sizes[0];

    char* ws = (char*)d_ws;
    size_t off = 0;
    unsigned* ppack = (unsigned*)(ws + off); off += (size_t)ABLOCKS * TMAX * sizeof(unsigned);
    float*    pevr  = (float*)(ws + off);    off += ABLOCKS * sizeof(float);
    float*    bsum  = (float*)(ws + off);    off += TMAX * sizeof(float);
    unsigned* bcnt  = (unsigned*)(ws + off); off += TMAX * sizeof(unsigned);
    unsigned* done  = (unsigned*)(ws + off); off += sizeof(unsigned);

    if (n == ABLOCKS * ATHREADS * 4 * PERTHREAD_V4) {
        coxph_hist_fixed<<<ABLOCKS, ATHREADS, 0, stream>>>(
            risk, time_, event, ppack, pevr, done);
    } else {
        coxph_hist_generic<<<ABLOCKS, ATHREADS, 0, stream>>>(
            risk, time_, event, ppack, pevr, done, n);
    }
    coxph_reduce_finalize<<<RBLOCKS, RS * RB, 0, stream>>>(
        ppack, pevr, bsum, bcnt, done, out);
}

// Round 6
// 128.984 us; speedup vs baseline: 1.1791x; 1.1791x over previous
//
#include <hip/hip_runtime.h>
#include <hip/hip_fp16.h>

#define TMAX 4096
#define ABLOCKS 512          // hist grid: 2 blocks/CU -> 32 waves/CU
#define ATHREADS 1024
#define NWAVES (ATHREADS / 64)
#define PERTHREAD_V4 4       // fast path: 4 x float4 per thread (16 samples)

#define SCALE_F 1048576.0f   // 2^20 fixed-point scale
#define INV_SCALE 9.5367431640625e-07f  // 1/2^20 (exact in f32)
#define SUM_MASK 0xFFFFFFFFFFFFULL      // low 48 bits
#define CNT_SHIFT 48

// reduce decomposition: RB buckets per block (one per lane -> 256B coalesced
// wave reads), RS row-slices per bucket
#define RB 64
#define RS 16
#define RBLOCKS (TMAX / RB)  // 64

// ---------------------------------------------------------------------------
// Kernel A: per-block LDS histogram. ONE ds_add_u64 per sample:
// low 48 bits = fixed-point sum of exp(r)*2^20, bits 48+ = event count.
// DUAL sub-histograms (waves 0-7 -> A, 8-15 -> B; 64 KB LDS) halve
// inter-wave same-bucket serialization. Per-wave event-risk sums bypass LDS
// (straight to pevr_waves). Flush: packed u32 (cnt<<16 | f16(sum)).
// Block 0 zeroes the cross-block `done` counter for kernel B.
// ---------------------------------------------------------------------------
__global__ __launch_bounds__(ATHREADS, 8) void coxph_hist_fixed(
    const float* __restrict__ risk, const int* __restrict__ time_,
    const int* __restrict__ event,
    unsigned* __restrict__ ppack, float* __restrict__ pevr_waves,
    unsigned* __restrict__ done)
{
    __shared__ unsigned long long s_acc[2 * TMAX];   // 64 KB exactly

    const int tid = threadIdx.x;
    if (blockIdx.x == 0 && tid == 0) *done = 0u;
    #pragma unroll
    for (int k = 0; k < 2 * TMAX / ATHREADS; ++k) s_acc[tid + k * ATHREADS] = 0ull;
    __syncthreads();

    const int lane = tid & 63, wave = tid >> 6;
    unsigned long long* __restrict__ hist = s_acc + ((wave >= NWAVES / 2) ? TMAX : 0);

    const float4* r4 = (const float4*)risk;
    const int4*   t4 = (const int4*)time_;
    const int4*   e4 = (const int4*)event;

    const int base = blockIdx.x * ATHREADS + tid;     // vec4 index
    const int STRIDE4 = ABLOCKS * ATHREADS;           // vec4 stride

    float4 r[PERTHREAD_V4]; int4 t[PERTHREAD_V4]; int4 e[PERTHREAD_V4];
    #pragma unroll
    for (int k = 0; k < PERTHREAD_V4; ++k) {
        const int i = base + k * STRIDE4;
        r[k] = r4[i]; t[k] = t4[i]; e[k] = e4[i];
    }

    float evr = 0.f;
    #pragma unroll
    for (int k = 0; k < PERTHREAD_V4; ++k) {
        {
            unsigned lo = (unsigned)(__expf(r[k].x) * SCALE_F + 0.5f);
            unsigned long long pk = ((unsigned long long)(unsigned)e[k].x << CNT_SHIFT) | lo;
            atomicAdd(&hist[t[k].x & (TMAX - 1)], pk);
            evr += e[k].x ? r[k].x : 0.f;
        }
        {
            unsigned lo = (unsigned)(__expf(r[k].y) * SCALE_F + 0.5f);
            unsigned long long pk = ((unsigned long long)(unsigned)e[k].y << CNT_SHIFT) | lo;
            atomicAdd(&hist[t[k].y & (TMAX - 1)], pk);
            evr += e[k].y ? r[k].y : 0.f;
        }
        {
            unsigned lo = (unsigned)(__expf(r[k].z) * SCALE_F + 0.5f);
            unsigned long long pk = ((unsigned long long)(unsigned)e[k].z << CNT_SHIFT) | lo;
            atomicAdd(&hist[t[k].z & (TMAX - 1)], pk);
            evr += e[k].z ? r[k].z : 0.f;
        }
        {
            unsigned lo = (unsigned)(__expf(r[k].w) * SCALE_F + 0.5f);
            unsigned long long pk = ((unsigned long long)(unsigned)e[k].w << CNT_SHIFT) | lo;
            atomicAdd(&hist[t[k].w & (TMAX - 1)], pk);
            evr += e[k].w ? r[k].w : 0.f;
        }
    }

    // wave-level reduce of event-risk sum -> straight to global (no LDS)
    #pragma unroll
    for (int off = 32; off > 0; off >>= 1) evr += __shfl_down(evr, off);
    if (lane == 0) pevr_waves[blockIdx.x * NWAVES + wave] = evr;
    __syncthreads();

    unsigned* pp = ppack + (size_t)blockIdx.x * TMAX;
    #pragma unroll
    for (int k = 0; k < TMAX / ATHREADS; ++k) {
        const int i = tid + k * ATHREADS;
        unsigned long long v = s_acc[i] + s_acc[i + TMAX];  // merge sub-hists
        float s = (float)(v & SUM_MASK) * INV_SCALE;        // ~O(10): f16-safe
        unsigned c = (unsigned)(v >> CNT_SHIFT);            // <= 16384: u16-safe
        unsigned hb = (unsigned)__half_as_ushort(__float2half(s));
        pp[i] = (c << 16) | hb;
    }
}

// ---------------------------------------------------------------------------
// Kernel A' (generic fallback, any n): grid-stride, single u64 histogram.
// ---------------------------------------------------------------------------
__global__ __launch_bounds__(ATHREADS, 8) void coxph_hist_generic(
    const float* __restrict__ risk, const int* __restrict__ time_,
    const int* __restrict__ event,
    unsigned* __restrict__ ppack, float* __restrict__ pevr_waves,
    unsigned* __restrict__ done, int n)
{
    __shared__ unsigned long long s_acc[TMAX];

    const int tid = threadIdx.x;
    if (blockIdx.x == 0 && tid == 0) *done = 0u;
    #pragma unroll
    for (int k = 0; k < TMAX / ATHREADS; ++k) s_acc[tid + k * ATHREADS] = 0ull;
    __syncthreads();

    float evr = 0.f;
    const int stride = gridDim.x * ATHREADS;
    for (int i = blockIdx.x * ATHREADS + tid; i < n; i += stride) {
        float rv = risk[i];
        int   ev = event[i];
        unsigned lo = (unsigned)(__expf(rv) * SCALE_F + 0.5f);
        unsigned long long pk = ((unsigned long long)(unsigned)ev << CNT_SHIFT) | lo;
        atomicAdd(&s_acc[time_[i] & (TMAX - 1)], pk);
        evr += ev ? rv : 0.f;
    }

    #pragma unroll
    for (int off = 32; off > 0; off >>= 1) evr += __shfl_down(evr, off);
    const int lane = tid & 63, wave = tid >> 6;
    if (lane == 0) pevr_waves[blockIdx.x * NWAVES + wave] = evr;
    __syncthreads();

    unsigned* pp = ppack + (size_t)blockIdx.x * TMAX;
    #pragma unroll
    for (int k = 0; k < TMAX / ATHREADS; ++k) {
        const int i = tid + k * ATHREADS;
        unsigned long long v = s_acc[i];
        float s = (float)(v & SUM_MASK) * INV_SCALE;
        unsigned c = (unsigned)(v >> CNT_SHIFT);
        unsigned hb = (unsigned)__half_as_ushort(__float2half(s));
        pp[i] = (c << 16) | hb;
    }
}

// ---------------------------------------------------------------------------
// Kernel B: reduce partials -> bucket sums/counts; the LAST block to finish
// (device-scope done counter) then performs the suffix-scan + nll finalize.
// 64 blocks x 1024: block owns 64 buckets (one per lane -> 256B coalesced
// wave reads), thread (s,j) sums a 32-row slice, LDS tree across 16 slices.
// ---------------------------------------------------------------------------
__global__ __launch_bounds__(1024) void coxph_reduce_finalize(
    const unsigned* __restrict__ ppack, const float* __restrict__ pevr_waves,
    float* __restrict__ bsum, unsigned* __restrict__ bcnt,
    unsigned* __restrict__ done, float* __restrict__ out)
{
    __shared__ float    ls[RS * RB];
    __shared__ unsigned lc[RS * RB];
    __shared__ unsigned s_last;

    const int t = threadIdx.x;
    const int j = t & (RB - 1);          // bucket lane 0..63
    const int s = t >> 6;                // slice 0..15
    const int bucket = blockIdx.x * RB + j;

    float sum = 0.f; unsigned cnt = 0u;
    #pragma unroll
    for (int k = 0; k < ABLOCKS / RS; ++k) {   // 32 rows per slice
        const int row = s * (ABLOCKS / RS) + k;
        unsigned p = ppack[(size_t)row * TMAX + bucket];
        sum += __half2float(__ushort_as_half((unsigned short)(p & 0xFFFFu)));
        cnt += p >> 16;
    }
    ls[t] = sum; lc[t] = cnt;
    __syncthreads();

    #pragma unroll
    for (int h = RS / 2; h >= 1; h >>= 1) {
        if (s < h) { ls[t] += ls[t + h * RB]; lc[t] += lc[t + h * RB]; }
        __syncthreads();
    }
    if (s == 0) { bsum[bucket] = ls[j]; bcnt[bucket] = lc[j]; }
    __syncthreads();

    if (t == 0) {
        __threadfence();                  // device-scope release
        unsigned old = atomicAdd(done, 1u);
        s_last = (old == RBLOCKS - 1) ? 1u : 0u;
    }
    __syncthreads();
    if (!s_last) return;
    __threadfence();                      // device-scope acquire

    // ---- finalize: suffix-sum over 4096 buckets + nll, within this block ----
    __shared__ float    s_wsum[16];
    __shared__ double   s_dacc[16];
    __shared__ unsigned s_cacc[16];

    const int lane = t & 63, wave = t >> 6;
    const int j0 = 4 * t;
    float v0 = bsum[TMAX - 1 - j0];
    float v1 = bsum[TMAX - 2 - j0];
    float v2 = bsum[TMAX - 3 - j0];
    float v3 = bsum[TMAX - 4 - j0];
    float p0 = v0, p1 = p0 + v1, p2 = p1 + v2, p3 = p2 + v3;

    float t_incl = p3;
    #pragma unroll
    for (int off = 1; off < 64; off <<= 1) {
        float u = __shfl_up(t_incl, off);
        if (lane >= off) t_incl += u;
    }
    if (lane == 63) s_wsum[wave] = t_incl;
    __syncthreads();
    if (t == 0) {
        float acc = 0.f;
        for (int w = 0; w < 16; ++w) { float x = s_wsum[w]; s_wsum[w] = acc; acc += x; }
    }
    __syncthreads();
    const float excl = (t_incl - p3) + s_wsum[wave];

    double acc = 0.0;
    unsigned ctot = 0u;
    unsigned c0 = bcnt[TMAX - 1 - j0];
    unsigned c1 = bcnt[TMAX - 2 - j0];
    unsigned c2 = bcnt[TMAX - 3 - j0];
    unsigned c3 = bcnt[TMAX - 4 - j0];
    if (c0) { acc += (double)c0 * (double)logf(excl + p0); ctot += c0; }
    if (c1) { acc += (double)c1 * (double)logf(excl + p1); ctot += c1; }
    if (c2) { acc += (double)c2 * (double)logf(excl + p2); ctot += c2; }
    if (c3) { acc += (double)c3 * (double)logf(excl + p3); ctot += c3; }

    // subtract per-wave event-risk sums: 8192 entries, 8 per thread
    {
        float ev = 0.f;
        #pragma unroll
        for (int k = 0; k < (ABLOCKS * NWAVES) / 1024; ++k)
            ev += pevr_waves[t * ((ABLOCKS * NWAVES) / 1024) + k];
        acc -= (double)ev;
    }

    #pragma unroll
    for (int off = 32; off > 0; off >>= 1) {
        acc  += __shfl_down(acc, off);
        ctot += __shfl_down(ctot, off);
    }
    if (lane == 0) { s_dacc[wave] = acc; s_cacc[wave] = ctot; }
    __syncthreads();
    if (t == 0) {
        double a = 0.0; unsigned c = 0u;
        for (int w = 0; w < 16; ++w) { a += s_dacc[w]; c += s_cacc[w]; }
        out[0] = c ? (float)a : 0.0f;
    }
}

// ---------------------------------------------------------------------------
extern "C" void kernel_launch(void* const* d_in, const int* in_sizes, int n_in,
                              void* d_out, int out_size, void* d_ws, size_t ws_size,
                              hipStream_t stream)
{
    const float* risk  = (const float*)d_in[0];
    const int*   time_ = (const int*)d_in[1];
    const int*   event = (const int*)d_in[2];
    float* out = (float*)d_out;
    const int n = in_sizes[0];

    char* ws = (char*)d_ws;
    size_t off = 0;
    unsigned* ppack = (unsigned*)(ws + off); off += (size_t)ABLOCKS * TMAX * sizeof(unsigned);
    float*    pevr  = (float*)(ws + off);    off += (size_t)ABLOCKS * NWAVES * sizeof(float);
    float*    bsum  = (float*)(ws + off);    off += TMAX * sizeof(float);
    unsigned* bcnt  = (unsigned*)(ws + off); off += TMAX * sizeof(unsigned);
    unsigned* done  = (unsigned*)(ws + off); off += sizeof(unsigned);

    if (n == ABLOCKS * ATHREADS * 4 * PERTHREAD_V4) {
        coxph_hist_fixed<<<ABLOCKS, ATHREADS, 0, stream>>>(
            risk, time_, event, ppack, pevr, done);
    } else {
        coxph_hist_generic<<<ABLOCKS, ATHREADS, 0, stream>>>(
            risk, time_, event, ppack, pevr, done, n);
    }
    coxph_reduce_finalize<<<RBLOCKS, RS * RB, 0, stream>>>(
        ppack, pevr, bsum, bcnt, done, out);
}

// Round 7
// 123.494 us; speedup vs baseline: 1.2315x; 1.0445x over previous
//
#include <hip/hip_runtime.h>

#define TMAX 4096
#define ABLOCKS 512          // hist grid: 2 blocks/CU -> 32 waves/CU
#define ATHREADS 1024
#define PERTHREAD_V4 4       // fast path: 4 x float4 per thread (16 samples)

#define SCALE_F 1048576.0f   // 2^20 fixed-point scale
#define INV_SCALE (1.0 / 1048576.0)
#define SUM_MASK 0xFFFFFFFFFFFFULL   // low 48 bits
#define CNT_SHIFT 48

// reduce decomposition: RB buckets per block, RS row-slices per bucket
#define RB 32
#define RS 32

// ---------------------------------------------------------------------------
// Kernel A (fast path, n == ABLOCKS*ATHREADS*16): per-block LDS histogram.
// Single u64 LDS atomic per sample: low 48 bits = fixed-point sum of exp(r),
// bits 48+ = event count. Fully unrolled fixed-trip loop -> 12 independent
// global loads in flight per thread.
// ---------------------------------------------------------------------------
__global__ __launch_bounds__(ATHREADS, 8) void coxph_hist_fixed(
    const float* __restrict__ risk, const int* __restrict__ time_,
    const int* __restrict__ event,
    float* __restrict__ psum, unsigned short* __restrict__ pcnt,
    float* __restrict__ pevr)
{
    __shared__ unsigned long long s_acc[TMAX];
    __shared__ float s_evr[ATHREADS / 64];

    const int tid = threadIdx.x;
    #pragma unroll
    for (int k = 0; k < TMAX / ATHREADS; ++k) s_acc[tid + k * ATHREADS] = 0ull;
    __syncthreads();

    const float4* r4 = (const float4*)risk;
    const int4*   t4 = (const int4*)time_;
    const int4*   e4 = (const int4*)event;

    const int base = blockIdx.x * ATHREADS + tid;     // vec4 index
    const int STRIDE4 = ABLOCKS * ATHREADS;           // vec4 stride

    float4 r[PERTHREAD_V4]; int4 t[PERTHREAD_V4]; int4 e[PERTHREAD_V4];
    #pragma unroll
    for (int k = 0; k < PERTHREAD_V4; ++k) {
        const int i = base + k * STRIDE4;
        r[k] = r4[i]; t[k] = t4[i]; e[k] = e4[i];
    }

    float evr = 0.f;
    #pragma unroll
    for (int k = 0; k < PERTHREAD_V4; ++k) {
        {
            unsigned long long pk =
                (unsigned long long)(__expf(r[k].x) * SCALE_F + 0.5f)
                | ((unsigned long long)(unsigned)e[k].x << CNT_SHIFT);
            atomicAdd(&s_acc[t[k].x & (TMAX - 1)], pk);
            evr += e[k].x ? r[k].x : 0.f;
        }
        {
            unsigned long long pk =
                (unsigned long long)(__expf(r[k].y) * SCALE_F + 0.5f)
                | ((unsigned long long)(unsigned)e[k].y << CNT_SHIFT);
            atomicAdd(&s_acc[t[k].y & (TMAX - 1)], pk);
            evr += e[k].y ? r[k].y : 0.f;
        }
        {
            unsigned long long pk =
                (unsigned long long)(__expf(r[k].z) * SCALE_F + 0.5f)
                | ((unsigned long long)(unsigned)e[k].z << CNT_SHIFT);
            atomicAdd(&s_acc[t[k].z & (TMAX - 1)], pk);
            evr += e[k].z ? r[k].z : 0.f;
        }
        {
            unsigned long long pk =
                (unsigned long long)(__expf(r[k].w) * SCALE_F + 0.5f)
                | ((unsigned long long)(unsigned)e[k].w << CNT_SHIFT);
            atomicAdd(&s_acc[t[k].w & (TMAX - 1)], pk);
            evr += e[k].w ? r[k].w : 0.f;
        }
    }

    // wave-level reduce of event-risk sum
    #pragma unroll
    for (int off = 32; off > 0; off >>= 1) evr += __shfl_down(evr, off);
    const int lane = tid & 63, wave = tid >> 6;
    if (lane == 0) s_evr[wave] = evr;
    __syncthreads();

    float*          ps = psum + (size_t)blockIdx.x * TMAX;
    unsigned short* pc = pcnt + (size_t)blockIdx.x * TMAX;
    #pragma unroll
    for (int k = 0; k < TMAX / ATHREADS; ++k) {
        const int i = tid + k * ATHREADS;
        unsigned long long v = s_acc[i];
        ps[i] = (float)((double)(v & SUM_MASK) * INV_SCALE);
        pc[i] = (unsigned short)(v >> CNT_SHIFT);
    }
    if (tid == 0) {
        float tot = 0.f;
        for (int w = 0; w < ATHREADS / 64; ++w) tot += s_evr[w];
        pevr[blockIdx.x] = tot;
    }
}

// ---------------------------------------------------------------------------
// Kernel A' (generic fallback, any n): grid-stride, same u64 LDS scheme.
// ---------------------------------------------------------------------------
__global__ __launch_bounds__(ATHREADS, 8) void coxph_hist_generic(
    const float* __restrict__ risk, const int* __restrict__ time_,
    const int* __restrict__ event,
    float* __restrict__ psum, unsigned short* __restrict__ pcnt,
    float* __restrict__ pevr, int n)
{
    __shared__ unsigned long long s_acc[TMAX];
    __shared__ float s_evr[ATHREADS / 64];

    const int tid = threadIdx.x;
    #pragma unroll
    for (int k = 0; k < TMAX / ATHREADS; ++k) s_acc[tid + k * ATHREADS] = 0ull;
    __syncthreads();

    float evr = 0.f;
    const int stride = gridDim.x * ATHREADS;
    for (int i = blockIdx.x * ATHREADS + tid; i < n; i += stride) {
        float rv = risk[i];
        int   ev = event[i];
        unsigned long long pk =
            (unsigned long long)(__expf(rv) * SCALE_F + 0.5f)
            | ((unsigned long long)(unsigned)ev << CNT_SHIFT);
        atomicAdd(&s_acc[time_[i] & (TMAX - 1)], pk);
        evr += ev ? rv : 0.f;
    }

    #pragma unroll
    for (int off = 32; off > 0; off >>= 1) evr += __shfl_down(evr, off);
    const int lane = tid & 63, wave = tid >> 6;
    if (lane == 0) s_evr[wave] = evr;
    __syncthreads();

    float*          ps = psum + (size_t)blockIdx.x * TMAX;
    unsigned short* pc = pcnt + (size_t)blockIdx.x * TMAX;
    #pragma unroll
    for (int k = 0; k < TMAX / ATHREADS; ++k) {
        const int i = tid + k * ATHREADS;
        unsigned long long v = s_acc[i];
        ps[i] = (float)((double)(v & SUM_MASK) * INV_SCALE);
        pc[i] = (unsigned short)(v >> CNT_SHIFT);
    }
    if (tid == 0) {
        float tot = 0.f;
        for (int w = 0; w < ATHREADS / 64; ++w) tot += s_evr[w];
        pevr[blockIdx.x] = tot;
    }
}

// ---------------------------------------------------------------------------
// Kernel B: reduce per-block partials -> final bucket sums/counts.
// 128 blocks x 1024 threads; block owns RB=32 buckets, thread (s,j) sums a
// 16-row slice of bucket j, then LDS tree across RS=32 slices.
// ---------------------------------------------------------------------------
__global__ __launch_bounds__(1024) void coxph_reduce(
    const float* __restrict__ psum, const unsigned short* __restrict__ pcnt,
    float* __restrict__ bsum, unsigned* __restrict__ bcnt)
{
    __shared__ float    ls[RS * RB];
    __shared__ unsigned lc[RS * RB];

    const int t = threadIdx.x;
    const int j = t & (RB - 1);          // bucket within block
    const int s = t >> 5;                // row slice 0..RS-1
    const int bucket = blockIdx.x * RB + j;

    float sum = 0.f; unsigned cnt = 0u;
    #pragma unroll
    for (int k = 0; k < ABLOCKS / RS; ++k) {
        const int row = s * (ABLOCKS / RS) + k;
        sum += psum[(size_t)row * TMAX + bucket];
        cnt += pcnt[(size_t)row * TMAX + bucket];
    }
    ls[t] = sum; lc[t] = cnt;
    __syncthreads();

    #pragma unroll
    for (int h = RS / 2; h >= 1; h >>= 1) {
        if (s < h) { ls[t] += ls[t + h * RB]; lc[t] += lc[t + h * RB]; }
        __syncthreads();
    }
    if (s == 0) { bsum[bucket] = ls[j]; bcnt[bucket] = lc[j]; }
}

// ---------------------------------------------------------------------------
// Kernel C: single block. Suffix-sum over 4096 buckets (two-level scan on the
// reversed array), then nll = sum_t C[t]*log(suffix[t]) - sum_{events} r.
// ---------------------------------------------------------------------------
__global__ __launch_bounds__(1024) void coxph_finalize(
    const float* __restrict__ bsum, const unsigned* __restrict__ bcnt,
    const float* __restrict__ pevr, int nevr, float* __restrict__ out)
{
    __shared__ float    s_wsum[16];
    __shared__ double   s_dacc[16];
    __shared__ unsigned s_cacc[16];

    const int tid = threadIdx.x;
    const int lane = tid & 63, wave = tid >> 6;

    const int j0 = 4 * tid;
    float v0 = bsum[TMAX - 1 - j0];
    float v1 = bsum[TMAX - 2 - j0];
    float v2 = bsum[TMAX - 3 - j0];
    float v3 = bsum[TMAX - 4 - j0];
    float p0 = v0, p1 = p0 + v1, p2 = p1 + v2, p3 = p2 + v3;

    float t_incl = p3;
    #pragma unroll
    for (int off = 1; off < 64; off <<= 1) {
        float u = __shfl_up(t_incl, off);
        if (lane >= off) t_incl += u;
    }
    if (lane == 63) s_wsum[wave] = t_incl;
    __syncthreads();
    if (tid == 0) {
        float acc = 0.f;
        for (int w = 0; w < 16; ++w) { float x = s_wsum[w]; s_wsum[w] = acc; acc += x; }
    }
    __syncthreads();
    const float excl = (t_incl - p3) + s_wsum[wave];

    double acc = 0.0;
    unsigned ctot = 0u;
    unsigned c0 = bcnt[TMAX - 1 - j0];
    unsigned c1 = bcnt[TMAX - 2 - j0];
    unsigned c2 = bcnt[TMAX - 3 - j0];
    unsigned c3 = bcnt[TMAX - 4 - j0];
    if (c0) { acc += (double)c0 * (double)logf(excl + p0); ctot += c0; }
    if (c1) { acc += (double)c1 * (double)logf(excl + p1); ctot += c1; }
    if (c2) { acc += (double)c2 * (double)logf(excl + p2); ctot += c2; }
    if (c3) { acc += (double)c3 * (double)logf(excl + p3); ctot += c3; }

    if (tid < nevr) acc -= (double)pevr[tid];

    #pragma unroll
    for (int off = 32; off > 0; off >>= 1) {
        acc  += __shfl_down(acc, off);
        ctot += __shfl_down(ctot, off);
    }
    if (lane == 0) { s_dacc[wave] = acc; s_cacc[wave] = ctot; }
    __syncthreads();
    if (tid == 0) {
        double a = 0.0; unsigned c = 0u;
        for (int w = 0; w < 16; ++w) { a += s_dacc[w]; c += s_cacc[w]; }
        out[0] = c ? (float)a : 0.0f;
    }
}

// ---------------------------------------------------------------------------
extern "C" void kernel_launch(void* const* d_in, const int* in_sizes, int n_in,
                              void* d_out, int out_size, void* d_ws, size_t ws_size,
                              hipStream_t stream)
{
    const float* risk  = (const float*)d_in[0];
    const int*   time_ = (const int*)d_in[1];
    const int*   event = (const int*)d_in[2];
    float* out = (float*)d_out;
    const int n = in_sizes[0];

    char* ws = (char*)d_ws;
    const size_t psum_bytes = (size_t)ABLOCKS * TMAX * sizeof(float);
    const size_t pcnt_bytes = (size_t)ABLOCKS * TMAX * sizeof(unsigned short);
    size_t off = 0;
    float*          psum = (float*)(ws + off);          off += psum_bytes;
    unsigned short* pcnt = (unsigned short*)(ws + off); off += pcnt_bytes;
    float*          pevr = (float*)(ws + off);          off += ABLOCKS * sizeof(float);
    float*          bsum = (float*)(ws + off);          off += TMAX * sizeof(float);
    unsigned*       bcnt = (unsigned*)(ws + off);       off += TMAX * sizeof(unsigned);

    if (n == ABLOCKS * ATHREADS * 4 * PERTHREAD_V4) {
        coxph_hist_fixed<<<ABLOCKS, ATHREADS, 0, stream>>>(
            risk, time_, event, psum, pcnt, pevr);
    } else {
        coxph_hist_generic<<<ABLOCKS, ATHREADS, 0, stream>>>(
            risk, time_, event, psum, pcnt, pevr, n);
    }
    coxph_reduce<<<TMAX / RB, RS * RB, 0, stream>>>(psum, pcnt, bsum, bcnt);
    coxph_finalize<<<1, 1024, 0, stream>>>(bsum, bcnt, pevr, ABLOCKS, out);
}